// Round 5
// baseline (343.380 us; speedup 1.0000x reference)
//
#include <hip/hip_runtime.h>
#include <hip/hip_fp16.h>
#include <cstdint>
#include <cstddef>

// ---------------------------------------------------------------------------
// BasicGNN fused pipeline (round 17):
//  * R16 post-mortem: byte-halving gave only -6us -> agg1 is L2 REQUEST/
//    SECTOR-rate bound (~100 sectors/node: cnt gather 33 + scp gather 33 +
//    payload 34). This round eliminates the metadata gathers entirely:
//    - cnt[dst] computed by global atomicAdd in stageA (L2 atomics, hidden
//      under co-gridded GEMM; prep inits cnt=1 incl. self).
//    - ELL entries widened to 8B {src, ws} where ws = rsqrt(cnt[src])*scp[src]
//      is packed by stageB (its 196-block launch idles the machine anyway;
//      the per-edge cnt/scp gathers hide there).
//    - agg1: weight rides with the entry -> payload-only gathers; payload
//      regrouped to 8 lanes x dwordx4 = full 128B row per instruction.
//  * z1 biased-uint8 + per-row scale (R16, verified): dequant via v_perm
//    0x6400|b == (fp16)(1024+b) -> v_fma_mix; bias via ws-sum correction.
//  * Predicted: agg1 ~56 -> ~30-38us; e2e 272 -> ~245-252; absmax ~2.4e-3.
// Constraints: N < 2^23 (packing); N=100k OK.
// MFMA layouts (HW-verified): A[m=lane&15][k=q*8+j], B[k=q*8+j][n=lane&15],
// C/D col=lane&15, row=q*4+reg (q=lane>>4).
// ---------------------------------------------------------------------------

#define BSH 9
#define BNODES (1 << BSH)
#define BPAD 16
#define BCAP 9216

typedef _Float16 half8 __attribute__((ext_vector_type(8)));
typedef float floatx4 __attribute__((ext_vector_type(4)));
typedef float floatv4 __attribute__((ext_vector_type(4)));
typedef int intv4 __attribute__((ext_vector_type(4)));
typedef unsigned int uintv4 __attribute__((ext_vector_type(4)));
typedef unsigned int uintv2 __attribute__((ext_vector_type(2)));

#define QK 0x64646464u    // fp16 exponent splice: 0x6400|b == (fp16)(1024+b)
#define SEL01 0x00050004u // perm: {q.b0, 0x64, q.b1, 0x64}
#define SEL23 0x00070006u // perm: {q.b2, 0x64, q.b3, 0x64}

// 8 x fp32 += w * fp16 halves of 4 dwords (v_fma_mix selects f16 via op_sel).
__device__ __forceinline__ void fmamix8(float* acc, uintv4 v, float w) {
  asm("v_fma_mix_f32 %0, %1, %2, %0 op_sel:[0,0,0] op_sel_hi:[0,1,0]"
      : "+v"(acc[0]) : "v"(w), "v"(v.x));
  asm("v_fma_mix_f32 %0, %1, %2, %0 op_sel:[0,1,0] op_sel_hi:[0,1,0]"
      : "+v"(acc[1]) : "v"(w), "v"(v.x));
  asm("v_fma_mix_f32 %0, %1, %2, %0 op_sel:[0,0,0] op_sel_hi:[0,1,0]"
      : "+v"(acc[2]) : "v"(w), "v"(v.y));
  asm("v_fma_mix_f32 %0, %1, %2, %0 op_sel:[0,1,0] op_sel_hi:[0,1,0]"
      : "+v"(acc[3]) : "v"(w), "v"(v.y));
  asm("v_fma_mix_f32 %0, %1, %2, %0 op_sel:[0,0,0] op_sel_hi:[0,1,0]"
      : "+v"(acc[4]) : "v"(w), "v"(v.z));
  asm("v_fma_mix_f32 %0, %1, %2, %0 op_sel:[0,1,0] op_sel_hi:[0,1,0]"
      : "+v"(acc[5]) : "v"(w), "v"(v.z));
  asm("v_fma_mix_f32 %0, %1, %2, %0 op_sel:[0,0,0] op_sel_hi:[0,1,0]"
      : "+v"(acc[6]) : "v"(w), "v"(v.w));
  asm("v_fma_mix_f32 %0, %1, %2, %0 op_sel:[0,1,0] op_sel_hi:[0,1,0]"
      : "+v"(acc[7]) : "v"(w), "v"(v.w));
}

// 16 features (one full dwordx4 of biased-uint8) -> acc[16].
__device__ __forceinline__ void fmaq16(float (&acc)[16], uintv4 q, float w) {
  uintv4 hwA, hwB;
  hwA.x = __builtin_amdgcn_perm(q.x, QK, SEL01);
  hwA.y = __builtin_amdgcn_perm(q.x, QK, SEL23);
  hwA.z = __builtin_amdgcn_perm(q.y, QK, SEL01);
  hwA.w = __builtin_amdgcn_perm(q.y, QK, SEL23);
  hwB.x = __builtin_amdgcn_perm(q.z, QK, SEL01);
  hwB.y = __builtin_amdgcn_perm(q.z, QK, SEL23);
  hwB.z = __builtin_amdgcn_perm(q.w, QK, SEL01);
  hwB.w = __builtin_amdgcn_perm(q.w, QK, SEL23);
  fmamix8(&acc[0], hwA, w);
  fmamix8(&acc[8], hwB, w);
}

#define SWZF(v, imm) \
  __int_as_float(__builtin_amdgcn_ds_swizzle(__float_as_int(v), imm))

// prep: W1 swizzle fp32->fp16 B-frag order; dummy row/meta; cnt=1; gcur=0.
__global__ __launch_bounds__(256) void prep_k(const float* __restrict__ W1,
                                              _Float16* __restrict__ wz,
                                              unsigned char* __restrict__ z1q8,
                                              float* __restrict__ z2w,
                                              int* __restrict__ cnt,
                                              int* __restrict__ gcur,
                                              int N, int NB) {
  int b = blockIdx.x, tid = threadIdx.x;
  if (b < 128) {
    int id = b * 256 + tid;
    int j = id & 7, lane = (id >> 3) & 63, nb = (id >> 9) & 7, kb = id >> 12;
    int k = kb * 32 + ((lane >> 4) << 3) + j;
    int n = nb * 16 + (lane & 15);
    wz[id] = (_Float16)W1[k * 128 + n];
  } else if (b == 128) {
    // dummy row N: bytes 128 (dequants to 0 with any ws), z2w dummy = 0
    if (tid < 32) ((unsigned*)(z1q8 + (size_t)N * 128))[tid] = 0x80808080u;
    if (tid == 0) z2w[N] = 0.f;
  } else {
    int CB = (N + 256) / 256;  // blocks covering N+1 cnt entries
    if (b < 129 + CB) {
      int i = (b - 129) * 256 + tid;
      if (i <= N) cnt[i] = 1;  // self-loop preseed; dummy N -> 1
    } else {
      int i = (b - 129 - CB) * 256 + tid;
      if (i < NB * BPAD) gcur[i] = 0;
    }
  }
}

// Co-grid stage kernel: blocks [0,fb) do fill-stage KIND; [fb,..) do GEMM
// tiles starting at tile g0.
template <int KIND>
__global__ __launch_bounds__(256) void stage_k(int fb, int g0,
                                               const float* __restrict__ X,
                                               const _Float16* __restrict__ wz,
                                               unsigned char* __restrict__ z1q8,
                                               float* __restrict__ scp, int N,
                                               const int* __restrict__ src,
                                               const int* __restrict__ dst,
                                               int* __restrict__ gcur,
                                               int* __restrict__ barr,
                                               uintv2* __restrict__ ell64,
                                               uintv2* __restrict__ ell2_64,
                                               int* __restrict__ cnt,
                                               int E, int NB) {
  __shared__ char lds_raw[16 * 1024 + 256];
  int tid = threadIdx.x;

  if ((int)blockIdx.x < fb) {
    if (KIND == 0) {
      // ---- stageA: scatter packed edges into bucket segments, 16 e/thr ----
      // Also: in-degree via global atomics (cnt preinit 1 by prep).
      int* bc = (int*)lds_raw;        // per-block bucket counts [<=512]
      int* bb = bc + 512;             // per-block bucket bases
      for (int i = tid; i < NB; i += 256) bc[i] = 0;
      __syncthreads();
      int base = ((int)blockIdx.x * 256 + tid) * 16;
      int dv[16], sv[16], rv[16], bkv[16];
      int ne = 0;
      if (base + 15 < E) {
#pragma unroll
        for (int q4 = 0; q4 < 4; ++q4) {
          intv4 d4 = __builtin_nontemporal_load((const intv4*)(dst + base + q4 * 4));
          intv4 s4 = __builtin_nontemporal_load((const intv4*)(src + base + q4 * 4));
          dv[q4 * 4 + 0] = d4[0]; dv[q4 * 4 + 1] = d4[1];
          dv[q4 * 4 + 2] = d4[2]; dv[q4 * 4 + 3] = d4[3];
          sv[q4 * 4 + 0] = s4[0]; sv[q4 * 4 + 1] = s4[1];
          sv[q4 * 4 + 2] = s4[2]; sv[q4 * 4 + 3] = s4[3];
        }
        ne = 16;
      } else {
        for (int e = base; e < E && e < base + 16; ++e) {
          dv[ne] = dst[e]; sv[ne] = src[e]; ++ne;
        }
      }
      for (int i = 0; i < ne; ++i) {
        bkv[i] = dv[i] >> BSH;
        rv[i] = atomicAdd(&bc[bkv[i]], 1);
        atomicAdd(&cnt[dv[i]], 1);            // in-degree (device-scope)
      }
      __syncthreads();
      for (int i = tid; i < NB; i += 256) {
        int cc = bc[i];
        bb[i] = cc ? atomicAdd(&gcur[i * BPAD], cc) : 0;
      }
      __syncthreads();
      for (int i = 0; i < ne; ++i) {
        int pos = bb[bkv[i]] + rv[i];
        if (pos < BCAP) {
          unsigned dl = (unsigned)(dv[i] & (BNODES - 1));
          barr[(size_t)bkv[i] * BCAP + pos] = (int)((dl << 23) | (unsigned)sv[i]);
        }
      }
    } else {
      // ---- stageB: bucket -> ELL64 {src, ws}; ws = rsqrt(cnt[s])*scp[s] ----
      // cnt (from stageA) and scp (from launch1 GEMM) are both final here.
      int* cl = (int*)lds_raw;  // BNODES slot counters
      int bkt = (int)blockIdx.x;
      int lo = bkt << BSH;
      for (int i = tid; i < BNODES; i += 256) {
        cl[i] = 1;
        int node = lo + i;
        if (node < N) {
          uintv2 en;
          en.x = (unsigned)node;
          en.y = (unsigned)__float_as_int(rsqrtf((float)cnt[node]) * scp[node]);
          ell64[(size_t)node * 32] = en;      // slot 0 = self
        }
      }
      __syncthreads();
      int cb = min(gcur[bkt * BPAD], BCAP);
      const int* seg = barr + (size_t)bkt * BCAP;
      for (int e = tid; e < cb; e += 256) {
        unsigned v = (unsigned)seg[e];
        int dl = (int)(v >> 23);
        int s = (int)(v & 0x7FFFFFu);
        float wsf = rsqrtf((float)cnt[s]) * scp[s];   // L2-hit gathers
        int p = atomicAdd(&cl[dl], 1);        // p >= 1 (slot 0 = self)
        uintv2 en;
        en.x = (unsigned)s;
        en.y = (unsigned)__float_as_int(wsf);
        if (p < 32) ell64[(size_t)(lo + dl) * 32 + p] = en;
        else if (p < 63) ell2_64[(size_t)(lo + dl) * 32 + (p - 32)] = en;
      }
    }
    return;
  }

  // ---- GEMM: tile M=64, N=128, K=256; four 16KB B-frag phases ----
  _Float16* Bl = (_Float16*)lds_raw;
  _Float16* Ol = (_Float16*)lds_raw;  // reused after MFMA: [64][128] fp16
  float* invl = (float*)(lds_raw + 16 * 1024);  // per-tile-row 126.5/rowmax

  int wave = tid >> 6, lane = tid & 63;
  int m = lane & 15, q = lane >> 4;
  int row0 = (g0 + (int)blockIdx.x - fb) * 64;
  int row = row0 + wave * 16 + m;

  floatx4 acc[8];
#pragma unroll
  for (int nb = 0; nb < 8; ++nb) acc[nb] = (floatx4)(0.f);

  const uintv4* wsrc = (const uintv4*)wz;
  uintv4* bdst = (uintv4*)Bl;

#pragma unroll
  for (int ph = 0; ph < 4; ++ph) {
    if (ph) __syncthreads();
#pragma unroll
    for (int i = 0; i < 4; ++i) bdst[i * 256 + tid] = wsrc[ph * 1024 + i * 256 + tid];
    __syncthreads();
#pragma unroll
    for (int kk = 0; kk < 2; ++kk) {
      int kb = ph * 2 + kk;
      half8 a;
      if (row < N) {
        const floatv4* ap = (const floatv4*)(X + (size_t)row * 256 + kb * 32 + q * 8);
        floatv4 a0 = __builtin_nontemporal_load(ap);
        floatv4 a1 = __builtin_nontemporal_load(ap + 1);
        a[0] = (_Float16)a0[0]; a[1] = (_Float16)a0[1];
        a[2] = (_Float16)a0[2]; a[3] = (_Float16)a0[3];
        a[4] = (_Float16)a1[0]; a[5] = (_Float16)a1[1];
        a[6] = (_Float16)a1[2]; a[7] = (_Float16)a1[3];
      } else {
#pragma unroll
        for (int j = 0; j < 8; ++j) a[j] = (_Float16)0.f;
      }
#pragma unroll
      for (int nb = 0; nb < 8; ++nb) {
        half8 b = *(const half8*)(Bl + ((size_t)(kk * 8 + nb) * 64 + lane) * 8);
        acc[nb] = __builtin_amdgcn_mfma_f32_16x16x32_f16(a, b, acc[nb], 0, 0, 0);
      }
    }
  }

  // ---- epilogue: per-row absmax -> scale; fp16 to LDS; quantized readout --
  float rmax[4];
#pragma unroll
  for (int r = 0; r < 4; ++r) rmax[r] = 1e-6f;
#pragma unroll
  for (int nb = 0; nb < 8; ++nb)
#pragma unroll
    for (int r = 0; r < 4; ++r) rmax[r] = fmaxf(rmax[r], fabsf(acc[nb][r]));
#pragma unroll
  for (int r = 0; r < 4; ++r) {  // reduce across the 16 m-lanes (q-group)
    float v = rmax[r];
    v = fmaxf(v, __shfl_xor(v, 1, 64));
    v = fmaxf(v, __shfl_xor(v, 2, 64));
    v = fmaxf(v, __shfl_xor(v, 4, 64));
    v = fmaxf(v, __shfl_xor(v, 8, 64));
    rmax[r] = v;
  }
  __syncthreads();  // all Bl reads done; LDS becomes Ol + invl

#pragma unroll
  for (int nb = 0; nb < 8; ++nb) {
    int col = nb * 16 + m;
#pragma unroll
    for (int r = 0; r < 4; ++r) {
      int orow = wave * 16 + q * 4 + r;
      Ol[orow * 128 + col] = (_Float16)acc[nb][r];
    }
  }
  if (m == 0) {
#pragma unroll
    for (int r = 0; r < 4; ++r) {
      int tr = wave * 16 + q * 4 + r;
      float inv = 126.5f / rmax[r];
      invl[tr] = inv;
      int rw = row0 + tr;
      if (rw < N) scp[rw] = rmax[r] * (1.f / 126.5f);
    }
  }
  __syncthreads();

  const uintv4* osrc = (const uintv4*)Ol;
#pragma unroll
  for (int i = 0; i < 4; ++i) {
    int idx = i * 256 + tid;
    int r = idx >> 4;       // tile row
    int fb8 = idx & 15;     // 8-feature block
    if (row0 + r < N) {
      uintv4 v = osrc[idx];
      half8 hv = __builtin_bit_cast(half8, v);
      float inv = invl[r];
      unsigned bq[8];
#pragma unroll
      for (int j = 0; j < 8; ++j) {
        // z*inv in [-126.5,126.5]; +1152 -> fp16 ulp 1.0 -> RTN to integer
        // grid; low byte == 128 + round(z*inv). (+1152.5 was the R15 bias bug)
        float t = fmaf((float)hv[j], inv, 1152.0f);
        _Float16 ht = (_Float16)t;
        bq[j] = (unsigned)__builtin_bit_cast(unsigned short, ht) & 0xFFu;
      }
      uintv2 o;
      o.x = bq[0] | (bq[1] << 8) | (bq[2] << 16) | (bq[3] << 24);
      o.y = bq[4] | (bq[5] << 8) | (bq[6] << 16) | (bq[7] << 24);
      *(uintv2*)(z1q8 + (size_t)(row0 + r) * 128 + fb8 * 8) = o;
    }
  }
}

// agg1: wave/node gather; weights ride in ELL64 entries (no metadata
// gathers). 8-lane groups x dwordx4 = one full 128B row per instruction;
// slots >= ct synthesize {N, 1.0} (dummy row contributes exactly 0 via the
// 1152*bs correction). acc[16]/lane; folds xor8/xor16 (swizzle) + xor32
// (bpermute). h = relu(dd*acc + b1); z2w[d] = dd*(h.W2).
__global__ __launch_bounds__(256) void agg1_k(const unsigned char* __restrict__ z1q8,
                                              const int* __restrict__ cnt,
                                              const uintv2* __restrict__ ell64,
                                              const uintv2* __restrict__ ell2_64,
                                              const float* __restrict__ b1,
                                              const float* __restrict__ W2,
                                              float* __restrict__ z2w, int N) {
  int d = blockIdx.x * 4 + (threadIdx.x >> 6);
  int lane = threadIdx.x & 63;
  if (d >= N) return;
  int cntd = cnt[d];                 // deg + 1 (incl. self)
  int ct = min(cntd, 63);
  uintv2 en;
  en.x = (unsigned)N; en.y = 0x3F800000u;  // {dummy, 1.0f}
  if (ct > 32) {  // rare: pull overflow entries into lanes 32..62
    if (lane < 32)      en = ell64[(size_t)d * 32 + lane];
    else if (lane < 63) en = ell2_64[(size_t)d * 32 + (lane - 32)];
  } else {        // common: lanes 32-63 duplicate low half
    en = ell64[(size_t)d * 32 + (lane & 31)];
  }
  int idx = (lane < ct) ? (int)en.x : N;
  float ws = (lane < ct) ? __int_as_float((int)en.y) : 1.0f;
  float dd = rsqrtf((float)cntd);
  int iw = __float_as_int(ws);

  int g = lane >> 3;                          // 8 slot-groups of 8 lanes
  unsigned a16 = (unsigned)(lane & 7) << 4;   // 16B col within 128B row
  const unsigned char* zb = z1q8;
  int ax = (lane ^ 32) << 2;                  // xor-32 fold address

  float acc[16];
#pragma unroll
  for (int k = 0; k < 16; ++k) acc[k] = 0.f;
  float bs = 0.f;                    // sum of ws (bias-128 correction)

  int t = 0;
  for (; t + 16 <= ct; t += 16) {    // 2 full-row gathers in flight
    int a0 = (t + g) << 2;
    int s0 = __builtin_amdgcn_ds_bpermute(a0, idx);
    int s1 = __builtin_amdgcn_ds_bpermute(a0 + 32, idx);
    float w0 = __int_as_float(__builtin_amdgcn_ds_bpermute(a0, iw));
    float w1 = __int_as_float(__builtin_amdgcn_ds_bpermute(a0 + 32, iw));
    uintv4 q0 = *(const uintv4*)(zb + (((unsigned)s0) << 7) + a16);
    uintv4 q1 = *(const uintv4*)(zb + (((unsigned)s1) << 7) + a16);
    fmaq16(acc, q0, w0);
    fmaq16(acc, q1, w1);
    bs += w0 + w1;
  }
  for (; t < ct; t += 8) {           // tail; slots >= ct are exact zeros
    int a0 = (t + g) << 2;
    int s0 = __builtin_amdgcn_ds_bpermute(a0, idx);
    float w0 = __int_as_float(__builtin_amdgcn_ds_bpermute(a0, iw));
    uintv4 q0 = *(const uintv4*)(zb + (((unsigned)s0) << 7) + a16);
    fmaq16(acc, q0, w0);
    bs += w0;
  }

  // fold the 8 slot-groups: xor8, xor16 via ds_swizzle; xor32 via bpermute
#pragma unroll
  for (int k = 0; k < 16; ++k) {
    float x = acc[k];
    x += SWZF(x, 0x201F);
    x += SWZF(x, 0x401F);
    x += __int_as_float(__builtin_amdgcn_ds_bpermute(ax, __float_as_int(x)));
    acc[k] = x;
  }
  bs += SWZF(bs, 0x201F);
  bs += SWZF(bs, 0x401F);
  bs += __int_as_float(__builtin_amdgcn_ds_bpermute(ax, __float_as_int(bs)));
  float corr = 1152.f * bs;  // subtract ws*(1024+128) per slot

  int fb = (lane & 7) * 16;
  const float* bp = b1 + fb;
  const float* wp = W2 + fb;
  float dot = 0.f;
#pragma unroll
  for (int k = 0; k < 16; ++k)
    dot += fmaxf(fmaf(dd, acc[k] - corr, bp[k]), 0.f) * wp[k];
  dot += SWZF(dot, 0x041F);
  dot += SWZF(dot, 0x081F);
  dot += SWZF(dot, 0x101F);
  if (lane == 0) z2w[d] = dd * dot;  // dinv[d]*z2[d]
}

// agg2: 2 nodes/wave (32 lanes each). Self included via ELL slot 0.
// out[d] = dinv[d] * sum_slots z2w[slot] + b2.
__global__ __launch_bounds__(256) void agg2_k(const float* __restrict__ z2w,
                                              const int* __restrict__ cnt,
                                              const uintv2* __restrict__ ell64,
                                              const uintv2* __restrict__ ell2_64,
                                              const float* __restrict__ b2,
                                              float* __restrict__ out, int N) {
  int wv = threadIdx.x >> 6;
  int half = (threadIdx.x >> 5) & 1;
  int j = threadIdx.x & 31;
  int d = blockIdx.x * 8 + wv * 2 + half;
  if (d >= N) return;
  int cd = cnt[d];                  // deg + 1
  int c = min(cd, 63);
  uintv2 e = ell64[(size_t)d * 32 + j];
  int idx = (j < min(c, 32)) ? (int)e.x : N;
  float v = z2w[idx];               // z2w[N] = 0 dummy
  if (c > 32 && j < c - 32) v += z2w[(int)ell2_64[(size_t)d * 32 + j].x];
#pragma unroll
  for (int off = 16; off >= 1; off >>= 1) v += __shfl_xor(v, off, 64);
  if (j == 0) out[d] = rsqrtf((float)cd) * v + b2[0];
}

extern "C" void kernel_launch(void* const* d_in, const int* in_sizes, int n_in,
                              void* d_out, int out_size, void* d_ws, size_t ws_size,
                              hipStream_t stream) {
  (void)n_in; (void)out_size; (void)ws_size;
  const float* x = (const float*)d_in[0];
  const int* edge = (const int*)d_in[1];   // harness delivers ints as int32
  const float* W1 = (const float*)d_in[2];
  const float* b1 = (const float*)d_in[3];
  const float* W2 = (const float*)d_in[4];
  const float* b2 = (const float*)d_in[5];
  float* out = (float*)d_out;

  const int D = 256, H = 128;
  int N = in_sizes[0] / D;
  int E = in_sizes[1] / 2;
  const int* srcp = edge;       // edge_index[0]
  const int* dstp = edge + E;   // edge_index[1]
  int NB = (N + BNODES - 1) >> BSH;   // 196 for N=100k

  char* ws = (char*)d_ws;
  size_t off = 0;
  auto alloc = [&](size_t bytes) -> void* {
    void* p = ws + off;
    off += (bytes + 255) & ~(size_t)255;
    return p;
  };
  int* cnt            = (int*)alloc((size_t)(N + 1) * 4);
  float* z2w          = (float*)alloc((size_t)(N + 1) * 4);
  float* scp          = (float*)alloc((size_t)(N + 1) * 4);
  uintv2* ell64       = (uintv2*)alloc((size_t)N * 32 * 8);       // 25.6 MB
  uintv2* ell2_64     = (uintv2*)alloc((size_t)N * 32 * 8);       // 25.6 MB (cold)
  _Float16* wz        = (_Float16*)alloc((size_t)32768 * 2);      // 64 KB
  unsigned char* z1q8 = (unsigned char*)alloc((size_t)(N + 1) * 128);  // 12.8 MB
  int* gcur           = (int*)alloc((size_t)NB * BPAD * 4);
  int* barr           = (int*)alloc((size_t)NB * BCAP * 4);       // 7.2 MB
  // total ~72 MB

  int tiles = (N + 63) / 64;
  int fbA = (E + 4095) / 4096;   // 16 edges/thread
  int fbB = NB;
  int CB = (N + 256) / 256;

  prep_k<<<dim3(129 + CB + (NB * BPAD + 255) / 256), dim3(256), 0, stream>>>(
      W1, wz, z1q8, z2w, cnt, gcur, N, NB);
  // launch1: stageA (+ cnt atomics) co-grid with ALL GEMM tiles.
  stage_k<0><<<dim3(fbA + tiles), dim3(256), 0, stream>>>(fbA, 0, x, wz, z1q8,
      scp, N, srcp, dstp, gcur, barr, ell64, ell2_64, cnt, E, NB);
  // launch2: stageB packs {src, ws} ELL64 (cnt+scp final here).
  stage_k<1><<<dim3(fbB), dim3(256), 0, stream>>>(fbB, tiles, x, wz, z1q8,
      scp, N, srcp, dstp, gcur, barr, ell64, ell2_64, cnt, E, NB);
  agg1_k<<<dim3((N + 3) / 4), dim3(256), 0, stream>>>(z1q8, cnt, ell64, ell2_64,
      b1, W2, z2w, N);
  agg2_k<<<dim3((N + 7) / 8), dim3(256), 0, stream>>>(z2w, cnt, ell64, ell2_64,
      b2, out, N);
}

// Round 7
// 287.399 us; speedup vs baseline: 1.1948x; 1.1948x over previous
//
#include <hip/hip_runtime.h>
#include <hip/hip_fp16.h>
#include <cstdint>
#include <cstddef>

// ---------------------------------------------------------------------------
// BasicGNN fused pipeline (round 18, resubmitted — R6 was a container
// failure, no kernel evidence):
//  * R17 post-mortem: per-edge global atomicAdd(cnt) poisoned stage1
//    (104us, all pipes idle = atomic-drain serialization at the barrier).
//    ELL64 8B entries also doubled agg1's stream. Both reverted.
//  * THIS round keeps R17's goal (kill agg1 metadata gathers) with zero
//    atomics: stageB's closing loop already holds final deg+1 in LDS (cl),
//    and scp is complete (ALL GEMM tiles ride launch1; R14: split is
//    perf-neutral). It emits wst[node] = rsqrt(cl)*scp[node] — a fused
//    weight table, streaming cost only. agg1 gathers ONE 4B table.
//    Sector model/node: R16 ~102 (payload 34+cnt 33+scp 33+ell 2) ->
//    ~69 (payload 34 + wst 33 + ell 2); wst is 400KB = L2-resident.
//  * agg1 payload: 8-lane groups x dwordx4 = full 128B row per instr (R17).
//  * z1 biased-uint8 + per-row scale (R16, verified): v_perm 0x6400|b ==
//    (fp16)(1024+b) -> v_fma_mix; bias via ws-sum correction (+1152.0,
//    NOT +1152.5 — R15's half-step bias bug).
// Constraints: N < 2^23 (packing); N=100k OK.
// MFMA layouts (HW-verified): A[m=lane&15][k=q*8+j], B[k=q*8+j][n=lane&15],
// C/D col=lane&15, row=q*4+reg (q=lane>>4).
// ---------------------------------------------------------------------------

#define BSH 9
#define BNODES (1 << BSH)
#define BPAD 16
#define BCAP 9216

typedef _Float16 half8 __attribute__((ext_vector_type(8)));
typedef float floatx4 __attribute__((ext_vector_type(4)));
typedef float floatv4 __attribute__((ext_vector_type(4)));
typedef int intv4 __attribute__((ext_vector_type(4)));
typedef unsigned int uintv4 __attribute__((ext_vector_type(4)));
typedef unsigned int uintv2 __attribute__((ext_vector_type(2)));

#define QK 0x64646464u    // fp16 exponent splice: 0x6400|b == (fp16)(1024+b)
#define SEL01 0x00050004u // perm: {q.b0, 0x64, q.b1, 0x64}
#define SEL23 0x00070006u // perm: {q.b2, 0x64, q.b3, 0x64}

// 8 x fp32 += w * fp16 halves of 4 dwords (v_fma_mix selects f16 via op_sel).
__device__ __forceinline__ void fmamix8(float* acc, uintv4 v, float w) {
  asm("v_fma_mix_f32 %0, %1, %2, %0 op_sel:[0,0,0] op_sel_hi:[0,1,0]"
      : "+v"(acc[0]) : "v"(w), "v"(v.x));
  asm("v_fma_mix_f32 %0, %1, %2, %0 op_sel:[0,1,0] op_sel_hi:[0,1,0]"
      : "+v"(acc[1]) : "v"(w), "v"(v.x));
  asm("v_fma_mix_f32 %0, %1, %2, %0 op_sel:[0,0,0] op_sel_hi:[0,1,0]"
      : "+v"(acc[2]) : "v"(w), "v"(v.y));
  asm("v_fma_mix_f32 %0, %1, %2, %0 op_sel:[0,1,0] op_sel_hi:[0,1,0]"
      : "+v"(acc[3]) : "v"(w), "v"(v.y));
  asm("v_fma_mix_f32 %0, %1, %2, %0 op_sel:[0,0,0] op_sel_hi:[0,1,0]"
      : "+v"(acc[4]) : "v"(w), "v"(v.z));
  asm("v_fma_mix_f32 %0, %1, %2, %0 op_sel:[0,1,0] op_sel_hi:[0,1,0]"
      : "+v"(acc[5]) : "v"(w), "v"(v.z));
  asm("v_fma_mix_f32 %0, %1, %2, %0 op_sel:[0,0,0] op_sel_hi:[0,1,0]"
      : "+v"(acc[6]) : "v"(w), "v"(v.w));
  asm("v_fma_mix_f32 %0, %1, %2, %0 op_sel:[0,1,0] op_sel_hi:[0,1,0]"
      : "+v"(acc[7]) : "v"(w), "v"(v.w));
}

// 16 features (one full dwordx4 of biased-uint8) -> acc[16].
__device__ __forceinline__ void fmaq16(float (&acc)[16], uintv4 q, float w) {
  uintv4 hwA, hwB;
  hwA.x = __builtin_amdgcn_perm(q.x, QK, SEL01);
  hwA.y = __builtin_amdgcn_perm(q.x, QK, SEL23);
  hwA.z = __builtin_amdgcn_perm(q.y, QK, SEL01);
  hwA.w = __builtin_amdgcn_perm(q.y, QK, SEL23);
  hwB.x = __builtin_amdgcn_perm(q.z, QK, SEL01);
  hwB.y = __builtin_amdgcn_perm(q.z, QK, SEL23);
  hwB.z = __builtin_amdgcn_perm(q.w, QK, SEL01);
  hwB.w = __builtin_amdgcn_perm(q.w, QK, SEL23);
  fmamix8(&acc[0], hwA, w);
  fmamix8(&acc[8], hwB, w);
}

#define SWZF(v, imm) \
  __int_as_float(__builtin_amdgcn_ds_swizzle(__float_as_int(v), imm))

// prep: W1 swizzle fp32->fp16 B-frag order; dummy row/meta; zero gcur.
__global__ __launch_bounds__(256) void prep_k(const float* __restrict__ W1,
                                              _Float16* __restrict__ wz,
                                              unsigned char* __restrict__ z1q8,
                                              float* __restrict__ wst,
                                              float* __restrict__ z2w,
                                              int* __restrict__ cnt,
                                              int* __restrict__ gcur,
                                              int N, int NB) {
  int b = blockIdx.x, tid = threadIdx.x;
  if (b < 128) {
    int id = b * 256 + tid;
    int j = id & 7, lane = (id >> 3) & 63, nb = (id >> 9) & 7, kb = id >> 12;
    int k = kb * 32 + ((lane >> 4) << 3) + j;
    int n = nb * 16 + (lane & 15);
    wz[id] = (_Float16)W1[k * 128 + n];
  } else if (b == 128) {
    // dummy row N: bytes 128 (dequants to exactly 0 with ws=1 via corr)
    if (tid < 32) ((unsigned*)(z1q8 + (size_t)N * 128))[tid] = 0x80808080u;
    if (tid == 0) { z2w[N] = 0.f; cnt[N] = 1; wst[N] = 1.f; }
  } else {
    int i = (b - 129) * 256 + tid;
    if (i < NB * BPAD) gcur[i] = 0;
  }
}

// Co-grid stage kernel: blocks [0,fb) do fill-stage KIND; [fb,..) do GEMM
// tiles starting at tile g0.
template <int KIND>
__global__ __launch_bounds__(256) void stage_k(int fb, int g0,
                                               const float* __restrict__ X,
                                               const _Float16* __restrict__ wz,
                                               unsigned char* __restrict__ z1q8,
                                               float* __restrict__ scp,
                                               float* __restrict__ wst, int N,
                                               const int* __restrict__ src,
                                               const int* __restrict__ dst,
                                               int* __restrict__ gcur,
                                               int* __restrict__ barr,
                                               int* __restrict__ ell,
                                               int* __restrict__ ell2,
                                               int* __restrict__ cnt,
                                               int E, int NB) {
  __shared__ char lds_raw[16 * 1024 + 256];
  int tid = threadIdx.x;

  if ((int)blockIdx.x < fb) {
    if (KIND == 0) {
      // ---- stageA: scatter packed edges into bucket segments, 16 e/thr ----
      // (no global atomics — R17 lesson)
      int* bc = (int*)lds_raw;        // per-block bucket counts [<=512]
      int* bb = bc + 512;             // per-block bucket bases
      for (int i = tid; i < NB; i += 256) bc[i] = 0;
      __syncthreads();
      int base = ((int)blockIdx.x * 256 + tid) * 16;
      int dv[16], sv[16], rv[16], bkv[16];
      int ne = 0;
      if (base + 15 < E) {
#pragma unroll
        for (int q4 = 0; q4 < 4; ++q4) {
          intv4 d4 = __builtin_nontemporal_load((const intv4*)(dst + base + q4 * 4));
          intv4 s4 = __builtin_nontemporal_load((const intv4*)(src + base + q4 * 4));
          dv[q4 * 4 + 0] = d4[0]; dv[q4 * 4 + 1] = d4[1];
          dv[q4 * 4 + 2] = d4[2]; dv[q4 * 4 + 3] = d4[3];
          sv[q4 * 4 + 0] = s4[0]; sv[q4 * 4 + 1] = s4[1];
          sv[q4 * 4 + 2] = s4[2]; sv[q4 * 4 + 3] = s4[3];
        }
        ne = 16;
      } else {
        for (int e = base; e < E && e < base + 16; ++e) {
          dv[ne] = dst[e]; sv[ne] = src[e]; ++ne;
        }
      }
      for (int i = 0; i < ne; ++i) {
        bkv[i] = dv[i] >> BSH;
        rv[i] = atomicAdd(&bc[bkv[i]], 1);
      }
      __syncthreads();
      for (int i = tid; i < NB; i += 256) {
        int cc = bc[i];
        bb[i] = cc ? atomicAdd(&gcur[i * BPAD], cc) : 0;
      }
      __syncthreads();
      for (int i = 0; i < ne; ++i) {
        int pos = bb[bkv[i]] + rv[i];
        if (pos < BCAP) {
          unsigned dl = (unsigned)(dv[i] & (BNODES - 1));
          barr[(size_t)bkv[i] * BCAP + pos] = (int)((dl << 23) | (unsigned)sv[i]);
        }
      }
    } else {
      // ---- stageB: bucket -> ELL(32)+ell2+cnt, then fused weight table ----
      // Self pre-seeded: cl init = 1, ell[node*32] = node, cnt = deg+1.
      // Closing loop: cl[i] is FINAL deg+1 and scp (launch1) is complete ->
      // wst[node] = rsqrt(cl)*scp[node] with streaming scp read. Zero atomics.
      int* cl = (int*)lds_raw;  // BNODES counters
      int bkt = (int)blockIdx.x;
      int lo = bkt << BSH;
      for (int i = tid; i < BNODES; i += 256) {
        cl[i] = 1;
        int node = lo + i;
        if (node < N) ell[(size_t)node * 32] = node;
      }
      __syncthreads();
      int cb = min(gcur[bkt * BPAD], BCAP);
      const int* seg = barr + (size_t)bkt * BCAP;
      for (int e = tid; e < cb; e += 256) {
        unsigned v = (unsigned)seg[e];
        int dl = (int)(v >> 23);
        int s = (int)(v & 0x7FFFFFu);
        int p = atomicAdd(&cl[dl], 1);          // p >= 1 (slot 0 = self)
        if (p < 32) ell[(size_t)(lo + dl) * 32 + p] = s;
        else if (p < 63) ell2[(size_t)(lo + dl) * 32 + (p - 32)] = s;
      }
      __syncthreads();
      for (int i = tid; i < BNODES; i += 256) {
        int node = lo + i;
        if (node < N) {
          int c = cl[i];
          cnt[node] = c;                        // deg + 1 (incl. self)
          wst[node] = rsqrtf((float)c) * scp[node];
        }
      }
    }
    return;
  }

  // ---- GEMM: tile M=64, N=128, K=256; four 16KB B-frag phases ----
  _Float16* Bl = (_Float16*)lds_raw;
  _Float16* Ol = (_Float16*)lds_raw;  // reused after MFMA: [64][128] fp16
  float* invl = (float*)(lds_raw + 16 * 1024);  // per-tile-row 126.5/rowmax

  int wave = tid >> 6, lane = tid & 63;
  int m = lane & 15, q = lane >> 4;
  int row0 = (g0 + (int)blockIdx.x - fb) * 64;
  int row = row0 + wave * 16 + m;

  floatx4 acc[8];
#pragma unroll
  for (int nb = 0; nb < 8; ++nb) acc[nb] = (floatx4)(0.f);

  const uintv4* wsrc = (const uintv4*)wz;
  uintv4* bdst = (uintv4*)Bl;

#pragma unroll
  for (int ph = 0; ph < 4; ++ph) {
    if (ph) __syncthreads();
#pragma unroll
    for (int i = 0; i < 4; ++i) bdst[i * 256 + tid] = wsrc[ph * 1024 + i * 256 + tid];
    __syncthreads();
#pragma unroll
    for (int kk = 0; kk < 2; ++kk) {
      int kb = ph * 2 + kk;
      half8 a;
      if (row < N) {
        const floatv4* ap = (const floatv4*)(X + (size_t)row * 256 + kb * 32 + q * 8);
        floatv4 a0 = __builtin_nontemporal_load(ap);
        floatv4 a1 = __builtin_nontemporal_load(ap + 1);
        a[0] = (_Float16)a0[0]; a[1] = (_Float16)a0[1];
        a[2] = (_Float16)a0[2]; a[3] = (_Float16)a0[3];
        a[4] = (_Float16)a1[0]; a[5] = (_Float16)a1[1];
        a[6] = (_Float16)a1[2]; a[7] = (_Float16)a1[3];
      } else {
#pragma unroll
        for (int j = 0; j < 8; ++j) a[j] = (_Float16)0.f;
      }
#pragma unroll
      for (int nb = 0; nb < 8; ++nb) {
        half8 b = *(const half8*)(Bl + ((size_t)(kk * 8 + nb) * 64 + lane) * 8);
        acc[nb] = __builtin_amdgcn_mfma_f32_16x16x32_f16(a, b, acc[nb], 0, 0, 0);
      }
    }
  }

  // ---- epilogue: per-row absmax -> scale; fp16 to LDS; quantized readout --
  float rmax[4];
#pragma unroll
  for (int r = 0; r < 4; ++r) rmax[r] = 1e-6f;
#pragma unroll
  for (int nb = 0; nb < 8; ++nb)
#pragma unroll
    for (int r = 0; r < 4; ++r) rmax[r] = fmaxf(rmax[r], fabsf(acc[nb][r]));
#pragma unroll
  for (int r = 0; r < 4; ++r) {  // reduce across the 16 m-lanes (q-group)
    float v = rmax[r];
    v = fmaxf(v, __shfl_xor(v, 1, 64));
    v = fmaxf(v, __shfl_xor(v, 2, 64));
    v = fmaxf(v, __shfl_xor(v, 4, 64));
    v = fmaxf(v, __shfl_xor(v, 8, 64));
    rmax[r] = v;
  }
  __syncthreads();  // all Bl reads done; LDS becomes Ol + invl

#pragma unroll
  for (int nb = 0; nb < 8; ++nb) {
    int col = nb * 16 + m;
#pragma unroll
    for (int r = 0; r < 4; ++r) {
      int orow = wave * 16 + q * 4 + r;
      Ol[orow * 128 + col] = (_Float16)acc[nb][r];
    }
  }
  if (m == 0) {
#pragma unroll
    for (int r = 0; r < 4; ++r) {
      int tr = wave * 16 + q * 4 + r;
      float inv = 126.5f / rmax[r];
      invl[tr] = inv;
      int rw = row0 + tr;
      if (rw < N) scp[rw] = rmax[r] * (1.f / 126.5f);
    }
  }
  __syncthreads();

  const uintv4* osrc = (const uintv4*)Ol;
#pragma unroll
  for (int i = 0; i < 4; ++i) {
    int idx = i * 256 + tid;
    int r = idx >> 4;       // tile row
    int fb8 = idx & 15;     // 8-feature block
    if (row0 + r < N) {
      uintv4 v = osrc[idx];
      half8 hv = __builtin_bit_cast(half8, v);
      float inv = invl[r];
      unsigned bq[8];
#pragma unroll
      for (int j = 0; j < 8; ++j) {
        // z*inv in [-126.5,126.5]; +1152 -> fp16 ulp 1.0 -> RTN to integer
        // grid; low byte == 128 + round(z*inv). (+1152.5 was the R15 bias bug)
        float t = fmaf((float)hv[j], inv, 1152.0f);
        _Float16 ht = (_Float16)t;
        bq[j] = (unsigned)__builtin_bit_cast(unsigned short, ht) & 0xFFu;
      }
      uintv2 o;
      o.x = bq[0] | (bq[1] << 8) | (bq[2] << 16) | (bq[3] << 24);
      o.y = bq[4] | (bq[5] << 8) | (bq[6] << 16) | (bq[7] << 24);
      *(uintv2*)(z1q8 + (size_t)(row0 + r) * 128 + fb8 * 8) = o;
    }
  }
}

// agg1: wave/node gather; ONE metadata gather (fused wst table, 400KB =
// L2-resident). 8-lane groups x dwordx4 = full 128B row per instruction;
// slots >= ct use {N, 1.0} (dummy row contributes exactly 0 via corr).
// acc[16]/lane; folds xor8/xor16 (swizzle) + xor32 (bpermute).
// h = relu(dd*acc + b1); z2w[d] = dd*(h.W2).
__global__ __launch_bounds__(256) void agg1_k(const unsigned char* __restrict__ z1q8,
                                              const float* __restrict__ wst,
                                              const int* __restrict__ cnt,
                                              const int* __restrict__ ell,
                                              const int* __restrict__ ell2,
                                              const float* __restrict__ b1,
                                              const float* __restrict__ W2,
                                              float* __restrict__ z2w, int N) {
  int d = blockIdx.x * 4 + (threadIdx.x >> 6);
  int lane = threadIdx.x & 63;
  if (d >= N) return;
  int cntd = cnt[d];                 // deg + 1 (incl. self)
  int ct = min(cntd, 63);
  int raw;
  if (ct > 32) {  // rare: pull overflow entries into lanes 32..62
    raw = (lane < 32) ? ell[(size_t)d * 32 + lane]
                      : (lane < 63 ? ell2[(size_t)d * 32 + (lane - 32)] : N);
  } else {        // common: lanes 32-63 duplicate low half
    raw = ell[(size_t)d * 32 + (lane & 31)];
  }
  int idx = (lane < ct) ? raw : N;
  float ws = (lane < ct) ? wst[idx] : 1.0f;   // single fused-table gather
  float dd = rsqrtf((float)cntd);
  int iw = __float_as_int(ws);

  int g = lane >> 3;                          // 8 slot-groups of 8 lanes
  unsigned a16 = (unsigned)(lane & 7) << 4;   // 16B col within 128B row
  const unsigned char* zb = z1q8;
  int ax = (lane ^ 32) << 2;                  // xor-32 fold address

  float acc[16];
#pragma unroll
  for (int k = 0; k < 16; ++k) acc[k] = 0.f;
  float bs = 0.f;                    // sum of ws (bias-128 correction)

  int t = 0;
  for (; t + 16 <= ct; t += 16) {    // 2 full-row gathers in flight
    int a0 = (t + g) << 2;
    int s0 = __builtin_amdgcn_ds_bpermute(a0, idx);
    int s1 = __builtin_amdgcn_ds_bpermute(a0 + 32, idx);
    float w0 = __int_as_float(__builtin_amdgcn_ds_bpermute(a0, iw));
    float w1 = __int_as_float(__builtin_amdgcn_ds_bpermute(a0 + 32, iw));
    uintv4 q0 = *(const uintv4*)(zb + (((unsigned)s0) << 7) + a16);
    uintv4 q1 = *(const uintv4*)(zb + (((unsigned)s1) << 7) + a16);
    fmaq16(acc, q0, w0);
    fmaq16(acc, q1, w1);
    bs += w0 + w1;
  }
  for (; t < ct; t += 8) {           // tail; slots >= ct are exact zeros
    int a0 = (t + g) << 2;
    int s0 = __builtin_amdgcn_ds_bpermute(a0, idx);
    float w0 = __int_as_float(__builtin_amdgcn_ds_bpermute(a0, iw));
    uintv4 q0 = *(const uintv4*)(zb + (((unsigned)s0) << 7) + a16);
    fmaq16(acc, q0, w0);
    bs += w0;
  }

  // fold the 8 slot-groups: xor8, xor16 via ds_swizzle; xor32 via bpermute
#pragma unroll
  for (int k = 0; k < 16; ++k) {
    float x = acc[k];
    x += SWZF(x, 0x201F);
    x += SWZF(x, 0x401F);
    x += __int_as_float(__builtin_amdgcn_ds_bpermute(ax, __float_as_int(x)));
    acc[k] = x;
  }
  bs += SWZF(bs, 0x201F);
  bs += SWZF(bs, 0x401F);
  bs += __int_as_float(__builtin_amdgcn_ds_bpermute(ax, __float_as_int(bs)));
  float corr = 1152.f * bs;  // subtract ws*(1024+128) per slot

  int fb = (lane & 7) * 16;
  const float* bp = b1 + fb;
  const float* wp = W2 + fb;
  float dot = 0.f;
#pragma unroll
  for (int k = 0; k < 16; ++k)
    dot += fmaxf(fmaf(dd, acc[k] - corr, bp[k]), 0.f) * wp[k];
  dot += SWZF(dot, 0x041F);
  dot += SWZF(dot, 0x081F);
  dot += SWZF(dot, 0x101F);
  if (lane == 0) z2w[d] = dd * dot;  // dinv[d]*z2[d]
}

// agg2: 2 nodes/wave (32 lanes each). Self included via ELL slot 0.
// out[d] = dinv[d] * sum_slots z2w[slot] + b2.
__global__ __launch_bounds__(256) void agg2_k(const float* __restrict__ z2w,
                                              const int* __restrict__ cnt,
                                              const int* __restrict__ ell,
                                              const int* __restrict__ ell2,
                                              const float* __restrict__ b2,
                                              float* __restrict__ out, int N) {
  int wv = threadIdx.x >> 6;
  int half = (threadIdx.x >> 5) & 1;
  int j = threadIdx.x & 31;
  int d = blockIdx.x * 8 + wv * 2 + half;
  if (d >= N) return;
  int cd = cnt[d];                  // deg + 1
  int c = min(cd, 63);
  int raw = ell[(size_t)d * 32 + j];
  int idx = (j < min(c, 32)) ? raw : N;
  float v = z2w[idx];               // z2w[N] = 0 dummy
  if (c > 32 && j < c - 32) v += z2w[ell2[(size_t)d * 32 + j]];
#pragma unroll
  for (int off = 16; off >= 1; off >>= 1) v += __shfl_xor(v, off, 64);
  if (j == 0) out[d] = rsqrtf((float)cd) * v + b2[0];
}

extern "C" void kernel_launch(void* const* d_in, const int* in_sizes, int n_in,
                              void* d_out, int out_size, void* d_ws, size_t ws_size,
                              hipStream_t stream) {
  (void)n_in; (void)out_size; (void)ws_size;
  const float* x = (const float*)d_in[0];
  const int* edge = (const int*)d_in[1];   // harness delivers ints as int32
  const float* W1 = (const float*)d_in[2];
  const float* b1 = (const float*)d_in[3];
  const float* W2 = (const float*)d_in[4];
  const float* b2 = (const float*)d_in[5];
  float* out = (float*)d_out;

  const int D = 256, H = 128;
  int N = in_sizes[0] / D;
  int E = in_sizes[1] / 2;
  const int* srcp = edge;       // edge_index[0]
  const int* dstp = edge + E;   // edge_index[1]
  int NB = (N + BNODES - 1) >> BSH;   // 196 for N=100k

  char* ws = (char*)d_ws;
  size_t off = 0;
  auto alloc = [&](size_t bytes) -> void* {
    void* p = ws + off;
    off += (bytes + 255) & ~(size_t)255;
    return p;
  };
  int* cnt            = (int*)alloc((size_t)(N + 1) * 4);
  float* z2w          = (float*)alloc((size_t)(N + 1) * 4);
  float* scp          = (float*)alloc((size_t)(N + 1) * 4);
  float* wst          = (float*)alloc((size_t)(N + 1) * 4);
  int* ell            = (int*)alloc((size_t)N * 32 * 4);          // 12.8 MB
  int* ell2           = (int*)alloc((size_t)N * 32 * 4);          // 12.8 MB (cold)
  _Float16* wz        = (_Float16*)alloc((size_t)32768 * 2);      // 64 KB
  unsigned char* z1q8 = (unsigned char*)alloc((size_t)(N + 1) * 128);  // 12.8 MB
  int* gcur           = (int*)alloc((size_t)NB * BPAD * 4);
  int* barr           = (int*)alloc((size_t)NB * BCAP * 4);       // 7.2 MB
  // total ~47 MB

  int tiles = (N + 63) / 64;
  int fbA = (E + 4095) / 4096;   // 16 edges/thread
  int fbB = NB;

  prep_k<<<dim3(129 + (NB * BPAD + 255) / 256), dim3(256), 0, stream>>>(
      W1, wz, z1q8, wst, z2w, cnt, gcur, N, NB);
  // launch1: stageA + ALL GEMM tiles (scp complete before launch2 — needed
  // so stageB can fuse wst; R14: tile placement is perf-neutral).
  stage_k<0><<<dim3(fbA + tiles), dim3(256), 0, stream>>>(fbA, 0, x, wz, z1q8,
      scp, wst, N, srcp, dstp, gcur, barr, ell, ell2, cnt, E, NB);
  // launch2: stageB alone (bucket->ELL + cnt + fused wst).
  stage_k<1><<<dim3(fbB), dim3(256), 0, stream>>>(fbB, tiles, x, wz, z1q8,
      scp, wst, N, srcp, dstp, gcur, barr, ell, ell2, cnt, E, NB);
  agg1_k<<<dim3((N + 3) / 4), dim3(256), 0, stream>>>(z1q8, wst, cnt, ell, ell2,
      b1, W2, z2w, N);
  agg2_k<<<dim3((N + 7) / 8), dim3(256), 0, stream>>>(z2w, cnt, ell, ell2, b2, out, N);
}

// Round 8
// 266.486 us; speedup vs baseline: 1.2885x; 1.0785x over previous
//
#include <hip/hip_runtime.h>
#include <hip/hip_fp16.h>
#include <cstdint>
#include <cstddef>

// ---------------------------------------------------------------------------
// BasicGNN fused pipeline (round 19):
//  * R18 post-mortem: fused wst table cut FETCH 193->89MB (model confirmed)
//    but the SIMULTANEOUS payload regroup (8-lane x dwordx4) halved in-flight
//    row-gathers 4->2 and agg1 went 62->76us. agg1 is outstanding-request /
//    latency bound, not byte bound (89MB @ 1.2TB/s = 15% HBM).
//  * THIS round: hybrid of proven halves. agg1 = R16's issue structure
//    VERBATIM (16-lane x 8B groups, 4 independent dwordx2 gathers + 4
//    weight bpermutes per 16-slot iteration, acc[8], xor16+xor32 folds)
//    + R18's single fused wst gather (no cnt/scp gathers).
//  * stageB emits wst[node] = rsqrt(cl)*scp[node] in its closing loop
//    (zero atomics; scp complete because ALL GEMM tiles ride launch1).
//  * z1 biased-uint8 + per-row scale: v_perm 0x6400|b == (fp16)(1024+b)
//    -> v_fma_mix; bias via ws-sum corr (+1152.0; +1152.5 was R15's bug).
// Constraints: N < 2^23 (packing); N=100k OK.
// MFMA layouts (HW-verified): A[m=lane&15][k=q*8+j], B[k=q*8+j][n=lane&15],
// C/D col=lane&15, row=q*4+reg (q=lane>>4).
// ---------------------------------------------------------------------------

#define BSH 9
#define BNODES (1 << BSH)
#define BPAD 16
#define BCAP 9216

typedef _Float16 half8 __attribute__((ext_vector_type(8)));
typedef float floatx4 __attribute__((ext_vector_type(4)));
typedef float floatv4 __attribute__((ext_vector_type(4)));
typedef int intv4 __attribute__((ext_vector_type(4)));
typedef unsigned int uintv4 __attribute__((ext_vector_type(4)));
typedef unsigned int uintv2 __attribute__((ext_vector_type(2)));

#define QK 0x64646464u    // fp16 exponent splice: 0x6400|b == (fp16)(1024+b)
#define SEL01 0x00050004u // perm: {q.b0, 0x64, q.b1, 0x64}
#define SEL23 0x00070006u // perm: {q.b2, 0x64, q.b3, 0x64}

// 8 x fp32 += w * fp16 halves of 4 dwords (v_fma_mix selects f16 via op_sel).
__device__ __forceinline__ void fmamix8(float* acc, uintv4 v, float w) {
  asm("v_fma_mix_f32 %0, %1, %2, %0 op_sel:[0,0,0] op_sel_hi:[0,1,0]"
      : "+v"(acc[0]) : "v"(w), "v"(v.x));
  asm("v_fma_mix_f32 %0, %1, %2, %0 op_sel:[0,1,0] op_sel_hi:[0,1,0]"
      : "+v"(acc[1]) : "v"(w), "v"(v.x));
  asm("v_fma_mix_f32 %0, %1, %2, %0 op_sel:[0,0,0] op_sel_hi:[0,1,0]"
      : "+v"(acc[2]) : "v"(w), "v"(v.y));
  asm("v_fma_mix_f32 %0, %1, %2, %0 op_sel:[0,1,0] op_sel_hi:[0,1,0]"
      : "+v"(acc[3]) : "v"(w), "v"(v.y));
  asm("v_fma_mix_f32 %0, %1, %2, %0 op_sel:[0,0,0] op_sel_hi:[0,1,0]"
      : "+v"(acc[4]) : "v"(w), "v"(v.z));
  asm("v_fma_mix_f32 %0, %1, %2, %0 op_sel:[0,1,0] op_sel_hi:[0,1,0]"
      : "+v"(acc[5]) : "v"(w), "v"(v.z));
  asm("v_fma_mix_f32 %0, %1, %2, %0 op_sel:[0,0,0] op_sel_hi:[0,1,0]"
      : "+v"(acc[6]) : "v"(w), "v"(v.w));
  asm("v_fma_mix_f32 %0, %1, %2, %0 op_sel:[0,1,0] op_sel_hi:[0,1,0]"
      : "+v"(acc[7]) : "v"(w), "v"(v.w));
}

// unpack 8 biased-uint8 (uintv2) -> 4 dwords of fp16 (1024+b) and accumulate.
__device__ __forceinline__ void fmaq8(float (&acc)[8], uintv2 q, float w) {
  uintv4 hw;
  hw.x = __builtin_amdgcn_perm(q.x, QK, SEL01);
  hw.y = __builtin_amdgcn_perm(q.x, QK, SEL23);
  hw.z = __builtin_amdgcn_perm(q.y, QK, SEL01);
  hw.w = __builtin_amdgcn_perm(q.y, QK, SEL23);
  fmamix8(acc, hw, w);
}

#define SWZF(v, imm) \
  __int_as_float(__builtin_amdgcn_ds_swizzle(__float_as_int(v), imm))

// prep: W1 swizzle fp32->fp16 B-frag order; dummy row/meta; zero gcur.
__global__ __launch_bounds__(256) void prep_k(const float* __restrict__ W1,
                                              _Float16* __restrict__ wz,
                                              unsigned char* __restrict__ z1q8,
                                              float* __restrict__ wst,
                                              float* __restrict__ z2w,
                                              int* __restrict__ cnt,
                                              int* __restrict__ gcur,
                                              int N, int NB) {
  int b = blockIdx.x, tid = threadIdx.x;
  if (b < 128) {
    int id = b * 256 + tid;
    int j = id & 7, lane = (id >> 3) & 63, nb = (id >> 9) & 7, kb = id >> 12;
    int k = kb * 32 + ((lane >> 4) << 3) + j;
    int n = nb * 16 + (lane & 15);
    wz[id] = (_Float16)W1[k * 128 + n];
  } else if (b == 128) {
    // dummy row N: bytes 128 (dequants to exactly 0 with ws=1 via corr)
    if (tid < 32) ((unsigned*)(z1q8 + (size_t)N * 128))[tid] = 0x80808080u;
    if (tid == 0) { z2w[N] = 0.f; cnt[N] = 1; wst[N] = 1.f; }
  } else {
    int i = (b - 129) * 256 + tid;
    if (i < NB * BPAD) gcur[i] = 0;
  }
}

// Co-grid stage kernel: blocks [0,fb) do fill-stage KIND; [fb,..) do GEMM
// tiles starting at tile g0.
template <int KIND>
__global__ __launch_bounds__(256) void stage_k(int fb, int g0,
                                               const float* __restrict__ X,
                                               const _Float16* __restrict__ wz,
                                               unsigned char* __restrict__ z1q8,
                                               float* __restrict__ scp,
                                               float* __restrict__ wst, int N,
                                               const int* __restrict__ src,
                                               const int* __restrict__ dst,
                                               int* __restrict__ gcur,
                                               int* __restrict__ barr,
                                               int* __restrict__ ell,
                                               int* __restrict__ ell2,
                                               int* __restrict__ cnt,
                                               int E, int NB) {
  __shared__ char lds_raw[16 * 1024 + 256];
  int tid = threadIdx.x;

  if ((int)blockIdx.x < fb) {
    if (KIND == 0) {
      // ---- stageA: scatter packed edges into bucket segments, 16 e/thr ----
      // (no global atomics — R17 lesson)
      int* bc = (int*)lds_raw;        // per-block bucket counts [<=512]
      int* bb = bc + 512;             // per-block bucket bases
      for (int i = tid; i < NB; i += 256) bc[i] = 0;
      __syncthreads();
      int base = ((int)blockIdx.x * 256 + tid) * 16;
      int dv[16], sv[16], rv[16], bkv[16];
      int ne = 0;
      if (base + 15 < E) {
#pragma unroll
        for (int q4 = 0; q4 < 4; ++q4) {
          intv4 d4 = __builtin_nontemporal_load((const intv4*)(dst + base + q4 * 4));
          intv4 s4 = __builtin_nontemporal_load((const intv4*)(src + base + q4 * 4));
          dv[q4 * 4 + 0] = d4[0]; dv[q4 * 4 + 1] = d4[1];
          dv[q4 * 4 + 2] = d4[2]; dv[q4 * 4 + 3] = d4[3];
          sv[q4 * 4 + 0] = s4[0]; sv[q4 * 4 + 1] = s4[1];
          sv[q4 * 4 + 2] = s4[2]; sv[q4 * 4 + 3] = s4[3];
        }
        ne = 16;
      } else {
        for (int e = base; e < E && e < base + 16; ++e) {
          dv[ne] = dst[e]; sv[ne] = src[e]; ++ne;
        }
      }
      for (int i = 0; i < ne; ++i) {
        bkv[i] = dv[i] >> BSH;
        rv[i] = atomicAdd(&bc[bkv[i]], 1);
      }
      __syncthreads();
      for (int i = tid; i < NB; i += 256) {
        int cc = bc[i];
        bb[i] = cc ? atomicAdd(&gcur[i * BPAD], cc) : 0;
      }
      __syncthreads();
      for (int i = 0; i < ne; ++i) {
        int pos = bb[bkv[i]] + rv[i];
        if (pos < BCAP) {
          unsigned dl = (unsigned)(dv[i] & (BNODES - 1));
          barr[(size_t)bkv[i] * BCAP + pos] = (int)((dl << 23) | (unsigned)sv[i]);
        }
      }
    } else {
      // ---- stageB: bucket -> ELL(32)+ell2+cnt, then fused weight table ----
      // Self pre-seeded: cl init = 1, ell[node*32] = node, cnt = deg+1.
      // Closing loop: cl[i] is FINAL deg+1 and scp (launch1) is complete ->
      // wst[node] = rsqrt(cl)*scp[node]. Zero atomics.
      int* cl = (int*)lds_raw;  // BNODES counters
      int bkt = (int)blockIdx.x;
      int lo = bkt << BSH;
      for (int i = tid; i < BNODES; i += 256) {
        cl[i] = 1;
        int node = lo + i;
        if (node < N) ell[(size_t)node * 32] = node;
      }
      __syncthreads();
      int cb = min(gcur[bkt * BPAD], BCAP);
      const int* seg = barr + (size_t)bkt * BCAP;
      for (int e = tid; e < cb; e += 256) {
        unsigned v = (unsigned)seg[e];
        int dl = (int)(v >> 23);
        int s = (int)(v & 0x7FFFFFu);
        int p = atomicAdd(&cl[dl], 1);          // p >= 1 (slot 0 = self)
        if (p < 32) ell[(size_t)(lo + dl) * 32 + p] = s;
        else if (p < 63) ell2[(size_t)(lo + dl) * 32 + (p - 32)] = s;
      }
      __syncthreads();
      for (int i = tid; i < BNODES; i += 256) {
        int node = lo + i;
        if (node < N) {
          int c = cl[i];
          cnt[node] = c;                        // deg + 1 (incl. self)
          wst[node] = rsqrtf((float)c) * scp[node];
        }
      }
    }
    return;
  }

  // ---- GEMM: tile M=64, N=128, K=256; four 16KB B-frag phases ----
  _Float16* Bl = (_Float16*)lds_raw;
  _Float16* Ol = (_Float16*)lds_raw;  // reused after MFMA: [64][128] fp16
  float* invl = (float*)(lds_raw + 16 * 1024);  // per-tile-row 126.5/rowmax

  int wave = tid >> 6, lane = tid & 63;
  int m = lane & 15, q = lane >> 4;
  int row0 = (g0 + (int)blockIdx.x - fb) * 64;
  int row = row0 + wave * 16 + m;

  floatx4 acc[8];
#pragma unroll
  for (int nb = 0; nb < 8; ++nb) acc[nb] = (floatx4)(0.f);

  const uintv4* wsrc = (const uintv4*)wz;
  uintv4* bdst = (uintv4*)Bl;

#pragma unroll
  for (int ph = 0; ph < 4; ++ph) {
    if (ph) __syncthreads();
#pragma unroll
    for (int i = 0; i < 4; ++i) bdst[i * 256 + tid] = wsrc[ph * 1024 + i * 256 + tid];
    __syncthreads();
#pragma unroll
    for (int kk = 0; kk < 2; ++kk) {
      int kb = ph * 2 + kk;
      half8 a;
      if (row < N) {
        const floatv4* ap = (const floatv4*)(X + (size_t)row * 256 + kb * 32 + q * 8);
        floatv4 a0 = __builtin_nontemporal_load(ap);
        floatv4 a1 = __builtin_nontemporal_load(ap + 1);
        a[0] = (_Float16)a0[0]; a[1] = (_Float16)a0[1];
        a[2] = (_Float16)a0[2]; a[3] = (_Float16)a0[3];
        a[4] = (_Float16)a1[0]; a[5] = (_Float16)a1[1];
        a[6] = (_Float16)a1[2]; a[7] = (_Float16)a1[3];
      } else {
#pragma unroll
        for (int j = 0; j < 8; ++j) a[j] = (_Float16)0.f;
      }
#pragma unroll
      for (int nb = 0; nb < 8; ++nb) {
        half8 b = *(const half8*)(Bl + ((size_t)(kk * 8 + nb) * 64 + lane) * 8);
        acc[nb] = __builtin_amdgcn_mfma_f32_16x16x32_f16(a, b, acc[nb], 0, 0, 0);
      }
    }
  }

  // ---- epilogue: per-row absmax -> scale; fp16 to LDS; quantized readout --
  float rmax[4];
#pragma unroll
  for (int r = 0; r < 4; ++r) rmax[r] = 1e-6f;
#pragma unroll
  for (int nb = 0; nb < 8; ++nb)
#pragma unroll
    for (int r = 0; r < 4; ++r) rmax[r] = fmaxf(rmax[r], fabsf(acc[nb][r]));
#pragma unroll
  for (int r = 0; r < 4; ++r) {  // reduce across the 16 m-lanes (q-group)
    float v = rmax[r];
    v = fmaxf(v, __shfl_xor(v, 1, 64));
    v = fmaxf(v, __shfl_xor(v, 2, 64));
    v = fmaxf(v, __shfl_xor(v, 4, 64));
    v = fmaxf(v, __shfl_xor(v, 8, 64));
    rmax[r] = v;
  }
  __syncthreads();  // all Bl reads done; LDS becomes Ol + invl

#pragma unroll
  for (int nb = 0; nb < 8; ++nb) {
    int col = nb * 16 + m;
#pragma unroll
    for (int r = 0; r < 4; ++r) {
      int orow = wave * 16 + q * 4 + r;
      Ol[orow * 128 + col] = (_Float16)acc[nb][r];
    }
  }
  if (m == 0) {
#pragma unroll
    for (int r = 0; r < 4; ++r) {
      int tr = wave * 16 + q * 4 + r;
      float inv = 126.5f / rmax[r];
      invl[tr] = inv;
      int rw = row0 + tr;
      if (rw < N) scp[rw] = rmax[r] * (1.f / 126.5f);
    }
  }
  __syncthreads();

  const uintv4* osrc = (const uintv4*)Ol;
#pragma unroll
  for (int i = 0; i < 4; ++i) {
    int idx = i * 256 + tid;
    int r = idx >> 4;       // tile row
    int fb8 = idx & 15;     // 8-feature block
    if (row0 + r < N) {
      uintv4 v = osrc[idx];
      half8 hv = __builtin_bit_cast(half8, v);
      float inv = invl[r];
      unsigned bq[8];
#pragma unroll
      for (int j = 0; j < 8; ++j) {
        // z*inv in [-126.5,126.5]; +1152 -> fp16 ulp 1.0 -> RTN to integer
        // grid; low byte == 128 + round(z*inv). (+1152.5 was the R15 bias bug)
        float t = fmaf((float)hv[j], inv, 1152.0f);
        _Float16 ht = (_Float16)t;
        bq[j] = (unsigned)__builtin_bit_cast(unsigned short, ht) & 0xFFu;
      }
      uintv2 o;
      o.x = bq[0] | (bq[1] << 8) | (bq[2] << 16) | (bq[3] << 24);
      o.y = bq[4] | (bq[5] << 8) | (bq[6] << 16) | (bq[7] << 24);
      *(uintv2*)(z1q8 + (size_t)(row0 + r) * 128 + fb8 * 8) = o;
    }
  }
}

// agg1: wave/node gather. R16 issue structure (16-lane x 8B groups, 4
// independent dwordx2 row-gathers + 4 weight bpermutes per 16-slot
// iteration) + single fused wst gather (R18). Slots >= ct use {N, 1.0}
// (dummy row bytes=128 contributes exactly 0 via corr). acc[8]/lane;
// folds xor16 (swizzle) + xor32 (bpermute).
// h = relu(dd*acc + b1); z2w[d] = dd*(h.W2).
__global__ __launch_bounds__(256) void agg1_k(const unsigned char* __restrict__ z1q8,
                                              const float* __restrict__ wst,
                                              const int* __restrict__ cnt,
                                              const int* __restrict__ ell,
                                              const int* __restrict__ ell2,
                                              const float* __restrict__ b1,
                                              const float* __restrict__ W2,
                                              float* __restrict__ z2w, int N) {
  int d = blockIdx.x * 4 + (threadIdx.x >> 6);
  int lane = threadIdx.x & 63;
  if (d >= N) return;
  int cntd = cnt[d];                 // deg + 1 (incl. self)
  int ct = min(cntd, 63);
  int raw;
  if (ct > 32) {  // rare: pull overflow entries into lanes 32..62
    raw = (lane < 32) ? ell[(size_t)d * 32 + lane]
                      : (lane < 63 ? ell2[(size_t)d * 32 + (lane - 32)] : N);
  } else {        // common: lanes 32-63 duplicate low half
    raw = ell[(size_t)d * 32 + (lane & 31)];
  }
  int idx = (lane < ct) ? raw : N;
  float ws = (lane < ct) ? wst[idx] : 1.0f;   // single fused-table gather
  float dd = rsqrtf((float)cntd);
  int iw = __float_as_int(ws);

  int g = lane >> 4;                           // 4 slot-groups of 16 lanes
  unsigned a8 = (unsigned)(lane & 15) << 3;    // 8B col within 128B row
  const unsigned char* zb = z1q8;
  int pa = g << 2;                   // bpermute byte-addr base for this group
  int ax = (lane ^ 32) << 2;         // xor-32 fold address (precomputed)

  float acc[8] = {0.f, 0.f, 0.f, 0.f, 0.f, 0.f, 0.f, 0.f};
  float bs = 0.f;                    // sum of ws (bias-128 correction)

  int t = 0;
  for (; t + 16 <= ct; t += 16) {    // 4 independent row-gathers in flight
    int a0 = pa + (t << 2);
    int s0 = __builtin_amdgcn_ds_bpermute(a0, idx);
    int s1 = __builtin_amdgcn_ds_bpermute(a0 + 16, idx);
    int s2 = __builtin_amdgcn_ds_bpermute(a0 + 32, idx);
    int s3 = __builtin_amdgcn_ds_bpermute(a0 + 48, idx);
    float w0 = __int_as_float(__builtin_amdgcn_ds_bpermute(a0, iw));
    float w1 = __int_as_float(__builtin_amdgcn_ds_bpermute(a0 + 16, iw));
    float w2 = __int_as_float(__builtin_amdgcn_ds_bpermute(a0 + 32, iw));
    float w3 = __int_as_float(__builtin_amdgcn_ds_bpermute(a0 + 48, iw));
    uintv2 q0 = *(const uintv2*)(zb + (((unsigned)s0) << 7) + a8);
    uintv2 q1 = *(const uintv2*)(zb + (((unsigned)s1) << 7) + a8);
    uintv2 q2 = *(const uintv2*)(zb + (((unsigned)s2) << 7) + a8);
    uintv2 q3 = *(const uintv2*)(zb + (((unsigned)s3) << 7) + a8);
    fmaq8(acc, q0, w0);
    fmaq8(acc, q1, w1);
    fmaq8(acc, q2, w2);
    fmaq8(acc, q3, w3);
    bs += (w0 + w1) + (w2 + w3);
  }
  for (; t < ct; t += 4) {  // tail; slots >= ct contribute exactly 0
    int a0 = pa + (t << 2);
    int s0 = __builtin_amdgcn_ds_bpermute(a0, idx);
    float w0 = __int_as_float(__builtin_amdgcn_ds_bpermute(a0, iw));
    uintv2 q0 = *(const uintv2*)(zb + (((unsigned)s0) << 7) + a8);
    fmaq8(acc, q0, w0);
    bs += w0;
  }

  // fold the 4 slot-groups: xor16 via ds_swizzle imm, xor32 via bpermute(ax)
#pragma unroll
  for (int k = 0; k < 8; ++k) {
    float x = acc[k];
    x += SWZF(x, 0x401F);
    x += __int_as_float(__builtin_amdgcn_ds_bpermute(ax, __float_as_int(x)));
    acc[k] = x;
  }
  bs += SWZF(bs, 0x401F);
  bs += __int_as_float(__builtin_amdgcn_ds_bpermute(ax, __float_as_int(bs)));
  float corr = 1152.f * bs;  // subtract ws*(1024+128) per slot

  int a8f = (lane & 15) * 8;
  float4 bA = *(const float4*)(b1 + a8f);
  float4 bB = *(const float4*)(b1 + a8f + 4);
  float4 wA = *(const float4*)(W2 + a8f);
  float4 wB = *(const float4*)(W2 + a8f + 4);
  float dot = fmaxf(fmaf(dd, acc[0] - corr, bA.x), 0.f) * wA.x
            + fmaxf(fmaf(dd, acc[1] - corr, bA.y), 0.f) * wA.y
            + fmaxf(fmaf(dd, acc[2] - corr, bA.z), 0.f) * wA.z
            + fmaxf(fmaf(dd, acc[3] - corr, bA.w), 0.f) * wA.w
            + fmaxf(fmaf(dd, acc[4] - corr, bB.x), 0.f) * wB.x
            + fmaxf(fmaf(dd, acc[5] - corr, bB.y), 0.f) * wB.y
            + fmaxf(fmaf(dd, acc[6] - corr, bB.z), 0.f) * wB.z
            + fmaxf(fmaf(dd, acc[7] - corr, bB.w), 0.f) * wB.w;
  dot += SWZF(dot, 0x201F);
  dot += SWZF(dot, 0x101F);
  dot += SWZF(dot, 0x081F);
  dot += SWZF(dot, 0x041F);
  if (lane == 0) z2w[d] = dd * dot;  // dinv[d]*z2[d]
}

// agg2: 2 nodes/wave (32 lanes each). Self included via ELL slot 0.
// out[d] = dinv[d] * sum_slots z2w[slot] + b2.
__global__ __launch_bounds__(256) void agg2_k(const float* __restrict__ z2w,
                                              const int* __restrict__ cnt,
                                              const int* __restrict__ ell,
                                              const int* __restrict__ ell2,
                                              const float* __restrict__ b2,
                                              float* __restrict__ out, int N) {
  int wv = threadIdx.x >> 6;
  int half = (threadIdx.x >> 5) & 1;
  int j = threadIdx.x & 31;
  int d = blockIdx.x * 8 + wv * 2 + half;
  if (d >= N) return;
  int cd = cnt[d];                  // deg + 1
  int c = min(cd, 63);
  int raw = ell[(size_t)d * 32 + j];
  int idx = (j < min(c, 32)) ? raw : N;
  float v = z2w[idx];               // z2w[N] = 0 dummy
  if (c > 32 && j < c - 32) v += z2w[ell2[(size_t)d * 32 + j]];
#pragma unroll
  for (int off = 16; off >= 1; off >>= 1) v += __shfl_xor(v, off, 64);
  if (j == 0) out[d] = rsqrtf((float)cd) * v + b2[0];
}

extern "C" void kernel_launch(void* const* d_in, const int* in_sizes, int n_in,
                              void* d_out, int out_size, void* d_ws, size_t ws_size,
                              hipStream_t stream) {
  (void)n_in; (void)out_size; (void)ws_size;
  const float* x = (const float*)d_in[0];
  const int* edge = (const int*)d_in[1];   // harness delivers ints as int32
  const float* W1 = (const float*)d_in[2];
  const float* b1 = (const float*)d_in[3];
  const float* W2 = (const float*)d_in[4];
  const float* b2 = (const float*)d_in[5];
  float* out = (float*)d_out;

  const int D = 256, H = 128;
  int N = in_sizes[0] / D;
  int E = in_sizes[1] / 2;
  const int* srcp = edge;       // edge_index[0]
  const int* dstp = edge + E;   // edge_index[1]
  int NB = (N + BNODES - 1) >> BSH;   // 196 for N=100k

  char* ws = (char*)d_ws;
  size_t off = 0;
  auto alloc = [&](size_t bytes) -> void* {
    void* p = ws + off;
    off += (bytes + 255) & ~(size_t)255;
    return p;
  };
  int* cnt            = (int*)alloc((size_t)(N + 1) * 4);
  float* z2w          = (float*)alloc((size_t)(N + 1) * 4);
  float* scp          = (float*)alloc((size_t)(N + 1) * 4);
  float* wst          = (float*)alloc((size_t)(N + 1) * 4);
  int* ell            = (int*)alloc((size_t)N * 32 * 4);          // 12.8 MB
  int* ell2           = (int*)alloc((size_t)N * 32 * 4);          // 12.8 MB (cold)
  _Float16* wz        = (_Float16*)alloc((size_t)32768 * 2);      // 64 KB
  unsigned char* z1q8 = (unsigned char*)alloc((size_t)(N + 1) * 128);  // 12.8 MB
  int* gcur           = (int*)alloc((size_t)NB * BPAD * 4);
  int* barr           = (int*)alloc((size_t)NB * BCAP * 4);       // 7.2 MB
  // total ~47 MB

  int tiles = (N + 63) / 64;
  int fbA = (E + 4095) / 4096;   // 16 edges/thread
  int fbB = NB;

  prep_k<<<dim3(129 + (NB * BPAD + 255) / 256), dim3(256), 0, stream>>>(
      W1, wz, z1q8, wst, z2w, cnt, gcur, N, NB);
  // launch1: stageA + ALL GEMM tiles (scp complete before launch2 — needed
  // so stageB can fuse wst; R14: tile placement is perf-neutral).
  stage_k<0><<<dim3(fbA + tiles), dim3(256), 0, stream>>>(fbA, 0, x, wz, z1q8,
      scp, wst, N, srcp, dstp, gcur, barr, ell, ell2, cnt, E, NB);
  // launch2: stageB alone (bucket->ELL + cnt + fused wst).
  stage_k<1><<<dim3(fbB), dim3(256), 0, stream>>>(fbB, tiles, x, wz, z1q8,
      scp, wst, N, srcp, dstp, gcur, barr, ell, ell2, cnt, E, NB);
  agg1_k<<<dim3((N + 3) / 4), dim3(256), 0, stream>>>(z1q8, wst, cnt, ell, ell2,
      b1, W2, z2w, N);
  agg2_k<<<dim3((N + 7) / 8), dim3(256), 0, stream>>>(z2w, cnt, ell, ell2, b2, out, N);
}